// Round 2
// baseline (1384.540 us; speedup 1.0000x reference)
//
#include <hip/hip_runtime.h>

#define T_TOK 16384
#define NCODE 8192
#define DIM   256
#define BN    64
#define ITERS (NCODE / BN)   // 128
#define WG_TOKS 64

typedef __attribute__((ext_vector_type(8))) short short8;
typedef __attribute__((ext_vector_type(4))) float floatx4;

__device__ __forceinline__ short f2bf(float x) {
  union { float f; unsigned u; } a; a.f = x;
  unsigned r = a.u + 0x7fffu + ((a.u >> 16) & 1u);   // RNE, no NaN inputs here
  return (short)(r >> 16);
}

// Prep: codebook fp32 -> bf16 copy + per-code squared norms.
// grid 2048 x 256 threads: one wave per code row (256 dims / 64 lanes = float4 each)
__global__ void vq_prep(const float* __restrict__ C, short* __restrict__ cbf,
                        float* __restrict__ cn) {
  int k = blockIdx.x * 4 + (threadIdx.x >> 6);
  int lane = threadIdx.x & 63;
  float4 v = *(const float4*)(C + k * DIM + lane * 4);
  short4 o;
  o.x = f2bf(v.x); o.y = f2bf(v.y); o.z = f2bf(v.z); o.w = f2bf(v.w);
  *(short4*)(cbf + k * DIM + lane * 4) = o;
  float d = v.x * v.x + v.y * v.y + v.z * v.z + v.w * v.w;
  #pragma unroll
  for (int s = 1; s < 64; s <<= 1) d += __shfl_xor(d, s);
  if (lane == 0) cn[k] = d;
}

// Tiled transpose: C fp32 [NCODE][DIM] -> cbfT bf16 [DIM][NCODE]
// grid (NCODE/64, DIM/64) x 256 threads; 64x64 tile via LDS.
__global__ void vq_tr(const float* __restrict__ C, short* __restrict__ cbfT) {
  __shared__ short t[64][72];   // [code][dim], pad 72 to break write/read conflicts
  const int c0 = blockIdx.x * 64, d0 = blockIdx.y * 64;
  const int tid = threadIdx.x;
  const int row = tid >> 2, seg = (tid & 3) * 16;
  #pragma unroll
  for (int i = 0; i < 16; i += 4) {
    float4 v = *(const float4*)(C + (c0 + row) * DIM + d0 + seg + i);
    t[row][seg + i + 0] = f2bf(v.x);
    t[row][seg + i + 1] = f2bf(v.y);
    t[row][seg + i + 2] = f2bf(v.z);
    t[row][seg + i + 3] = f2bf(v.w);
  }
  __syncthreads();
  // write: thread owns dim row (tid>>2), codes seg..seg+15
  short8 o0, o1;
  #pragma unroll
  for (int j = 0; j < 8; ++j) o0[j] = t[seg + j][row];
  #pragma unroll
  for (int j = 0; j < 8; ++j) o1[j] = t[seg + 8 + j][row];
  *(short8*)(cbfT + (d0 + row) * NCODE + c0 + seg) = o0;
  *(short8*)(cbfT + (d0 + row) * NCODE + c0 + seg + 8) = o1;
}

// Fused flash-style VQ, v2: 512 threads (8 waves), 64 tokens/WG, 256 WGs.
// S-phase B-frags direct from L2-resident cbf; PV B-frags direct from cbfT.
// Only the P round-trip uses LDS. u-noise register-pipelined one iter ahead.
__global__ __launch_bounds__(512, 2) void vq_main(
    const float* __restrict__ z, const float* __restrict__ u_noise,
    const short* __restrict__ cbf, const short* __restrict__ cbfT,
    const float* __restrict__ cn, float* __restrict__ out)
{
  __shared__ short pbuf[WG_TOKS][72];  // P chunk [token][code], 16B-aligned rows
  __shared__ float lred[2][WG_TOKS];
  __shared__ float lbuf[WG_TOKS];
  __shared__ float lossred[8];

  const int tid  = threadIdx.x;
  const int wid  = tid >> 6;
  const int lane = tid & 63;
  const int q    = lane >> 4;   // quad
  const int cl   = lane & 15;   // col-in-tile
  const int tokBase  = blockIdx.x * WG_TOKS;
  const int tokQ     = wid >> 1;          // S-phase: which 16 tokens (0..3)
  const int codeHalf = (wid & 1) * 32;    // S-phase: which 32 codes of the chunk
  const int dimBase  = wid * 32;          // PV-phase: which 32 dims

  // z A-fragments resident in registers: A[m=cl][k=q*8+j], 8 k-steps
  short8 za[8];
  {
    const float* zp = z + (tokBase + tokQ * 16 + cl) * DIM + q * 8;
    #pragma unroll
    for (int ks = 0; ks < 8; ++ks) {
      float4 f0 = *(const float4*)(zp + ks * 32);
      float4 f1 = *(const float4*)(zp + ks * 32 + 4);
      short8 t;
      t[0] = f2bf(f0.x); t[1] = f2bf(f0.y); t[2] = f2bf(f0.z); t[3] = f2bf(f0.w);
      t[4] = f2bf(f1.x); t[5] = f2bf(f1.y); t[6] = f2bf(f1.z); t[7] = f2bf(f1.w);
      za[ks] = t;
    }
  }

  // O accumulator: 64 tokens x 32 dims per wave (4x2 tiles)
  floatx4 Oa[4][2];
  #pragma unroll
  for (int a = 0; a < 4; ++a)
    #pragma unroll
    for (int b = 0; b < 2; ++b)
      Oa[a][b] = (floatx4){0.f, 0.f, 0.f, 0.f};
  float lpart[4] = {0.f, 0.f, 0.f, 0.f};

  // ---- u-noise + norms register pipeline (one iteration ahead) ----
  const float* ubase = u_noise + (tokBase + tokQ * 16 + q * 4) * NCODE;
  float uv[2][4], nk[2];
  #pragma unroll
  for (int nt = 0; nt < 2; ++nt) {
    int cG = codeHalf + nt * 16 + cl;      // it = 0
    nk[nt] = cn[cG];
    #pragma unroll
    for (int r = 0; r < 4; ++r) uv[nt][r] = ubase[r * NCODE + cG];
  }

  for (int it = 0; it < ITERS; ++it) {
    const int kb = it * BN;

    // ---- S phase: 16 tok x 32 codes per wave, K=256, B direct from L2 ----
    floatx4 acc[2];
    acc[0] = (floatx4){0.f, 0.f, 0.f, 0.f};
    acc[1] = (floatx4){0.f, 0.f, 0.f, 0.f};
    {
      const short* cb0 = cbf + (kb + codeHalf + cl) * DIM + q * 8;
      #pragma unroll
      for (int ks = 0; ks < 8; ++ks) {
        short8 b0 = *(const short8*)(cb0 + ks * 32);
        short8 b1 = *(const short8*)(cb0 + 16 * DIM + ks * 32);
        acc[0] = __builtin_amdgcn_mfma_f32_16x16x32_bf16(za[ks], b0, acc[0], 0, 0, 0);
        acc[1] = __builtin_amdgcn_mfma_f32_16x16x32_bf16(za[ks], b1, acc[1], 0, 0, 0);
      }
    }

    // ---- epilogue: p = exp(2 z.c - ||c||^2) * 1/(-log u) ----
    #pragma unroll
    for (int nt = 0; nt < 2; ++nt)
      #pragma unroll
      for (int r = 0; r < 4; ++r) {
        float nl = -__logf(uv[nt][r]);
        float p  = __expf(2.f * acc[nt][r] - nk[nt]) * __builtin_amdgcn_rcpf(nl);
        lpart[r] += p;
        pbuf[tokQ * 16 + q * 4 + r][codeHalf + nt * 16 + cl] = f2bf(p);
      }

    // ---- prefetch u/norms for next iter (branchless wrap; full PV+S cover) ----
    {
      int kbn = ((it + 1) & (ITERS - 1)) * BN;
      #pragma unroll
      for (int nt = 0; nt < 2; ++nt) {
        int cG = kbn + codeHalf + nt * 16 + cl;
        nk[nt] = cn[cG];
        #pragma unroll
        for (int r = 0; r < 4; ++r) uv[nt][r] = ubase[r * NCODE + cG];
      }
    }
    __syncthreads();

    // ---- PV phase: O(64 tok x 32 dims) += P(64x64) @ C(64 x dims), B from cbfT ----
    #pragma unroll
    for (int ks = 0; ks < 2; ++ks) {
      short8 pa[4];
      #pragma unroll
      for (int mt = 0; mt < 4; ++mt)
        pa[mt] = *(const short8*)&pbuf[mt * 16 + cl][ks * 32 + q * 8];
      #pragma unroll
      for (int nt = 0; nt < 2; ++nt) {
        short8 vb = *(const short8*)(cbfT + (dimBase + nt * 16 + cl) * NCODE +
                                     kb + ks * 32 + q * 8);
        #pragma unroll
        for (int mt = 0; mt < 4; ++mt)
          Oa[mt][nt] = __builtin_amdgcn_mfma_f32_16x16x32_bf16(pa[mt], vb, Oa[mt][nt], 0, 0, 0);
      }
    }
    __syncthreads();
  }

  // ---- reduce l across the 16 col-lanes of each quad, combine code-halves ----
  #pragma unroll
  for (int r = 0; r < 4; ++r) {
    float v = lpart[r];
    v += __shfl_xor(v, 1); v += __shfl_xor(v, 2);
    v += __shfl_xor(v, 4); v += __shfl_xor(v, 8);
    if (cl == 0) lred[wid & 1][tokQ * 16 + q * 4 + r] = v;
  }
  __syncthreads();
  if (tid < WG_TOKS) lbuf[tid] = lred[0][tid] + lred[1][tid];
  __syncthreads();

  // ---- normalize, store z_q, accumulate commit loss ----
  float lossAcc = 0.f;
  #pragma unroll
  for (int mt = 0; mt < 4; ++mt)
    #pragma unroll
    for (int nt = 0; nt < 2; ++nt)
      #pragma unroll
      for (int r = 0; r < 4; ++r) {
        int tokL = mt * 16 + q * 4 + r;
        int dimG = dimBase + nt * 16 + cl;
        float val = Oa[mt][nt][r] / lbuf[tokL];
        int off = (tokBase + tokL) * DIM + dimG;
        out[off] = val;
        float dd = val - z[off];
        lossAcc += dd * dd;
      }
  #pragma unroll
  for (int s = 32; s > 0; s >>= 1) lossAcc += __shfl_xor(lossAcc, s);
  if (lane == 0) lossred[wid] = lossAcc;
  __syncthreads();
  if (tid == 0) {
    float t = 0.f;
    #pragma unroll
    for (int w = 0; w < 8; ++w) t += lossred[w];
    atomicAdd(out + T_TOK * DIM, t * (2.f / (float)(T_TOK * DIM)));
  }
}

extern "C" void kernel_launch(void* const* d_in, const int* in_sizes, int n_in,
                              void* d_out, int out_size, void* d_ws, size_t ws_size,
                              hipStream_t stream) {
  const float* z = (const float*)d_in[0];       // [4,4096,256] fp32
  const float* C = (const float*)d_in[1];       // [8192,256]   fp32
  const float* u = (const float*)d_in[2];       // [16384,8192] fp32
  float* out = (float*)d_out;                   // [16384*256] z_q + [1] loss
  short* cbf  = (short*)d_ws;                                        // 4 MB bf16 [code][dim]
  short* cbfT = (short*)((char*)d_ws + (size_t)NCODE * DIM * 2);     // 4 MB bf16 [dim][code]
  float* cn   = (float*)((char*)d_ws + (size_t)NCODE * DIM * 4);     // 32 KB norms

  hipMemsetAsync(out + (size_t)T_TOK * DIM, 0, sizeof(float), stream);
  vq_prep<<<NCODE / 4, 256, 0, stream>>>(C, cbf, cn);
  vq_tr<<<dim3(NCODE / 64, DIM / 64), 256, 0, stream>>>(C, cbfT);
  vq_main<<<T_TOK / WG_TOKS, 512, 0, stream>>>(z, u, cbf, cbfT, cn, out);
}